// Round 17
// baseline (5940.657 us; speedup 1.0000x reference)
//
#include <hip/hip_runtime.h>
#include <hip/hip_bf16.h>

#define B_     2048
#define DIM_   1024
#define CLS_   1024
#define ODIM_  1024
#define DEPTH_ 4
#define SEQ_   8
#define INNER_ 128
#define DH_    64
#define FFI_   2048
#define ROT_   32
#define NSEG_  64

typedef _Float16 f16;
typedef f16 f16x4 __attribute__((ext_vector_type(4)));
typedef f16 f16x8 __attribute__((ext_vector_type(8)));
typedef float f32x4 __attribute__((ext_vector_type(4)));

#define SPLIT_SCALE 2048.0f
#define SPLIT_INV   (1.0f / 2048.0f)

__device__ __forceinline__ void split2(float x, f16& h, f16& l) {
  f16 hh = (f16)x;
  h = hh;
  l = (f16)((x - (float)hh) * SPLIT_SCALE);
}

// ---------------- threefry2x32 (matches jax._src.prng, 20 rounds) ----------------
__host__ __device__ inline void tf2x32(unsigned k0, unsigned k1, unsigned& x0, unsigned& x1)
{
  unsigned ks2 = k0 ^ k1 ^ 0x1BD11BDAu;
  x0 += k0; x1 += k1;
#define TFR(r) { x0 += x1; x1 = (x1 << (r)) | (x1 >> (32 - (r))); x1 ^= x0; }
  TFR(13) TFR(15) TFR(26) TFR(6)
  x0 += k1;  x1 += ks2 + 1u;
  TFR(17) TFR(29) TFR(16) TFR(24)
  x0 += ks2; x1 += k0 + 2u;
  TFR(13) TFR(15) TFR(26) TFR(6)
  x0 += k0;  x1 += k1 + 3u;
  TFR(17) TFR(29) TFR(16) TFR(24)
  x0 += k1;  x1 += ks2 + 4u;
  TFR(13) TFR(15) TFR(26) TFR(6)
  x0 += ks2; x1 += k0 + 5u;
#undef TFR
}

__device__ inline float gelu_tanh(float x) {
  float t = tanhf(0.7978845608028654f * (x + 0.044715f * (x * x * x)));
  return x * 0.5f * (1.0f + t);
}

// ---------------- rmsnorm (+optional fused feedback gather) -> f16 planes ----------------
__global__ __launch_bounds__(256) void rmsnorm_split_k(const float* __restrict__ x,
    const float* __restrict__ g, f16* __restrict__ nh, f16* __restrict__ nl,
    float* __restrict__ hout, const float* __restrict__ fbw,
    const int* __restrict__ idx_all, int step)
{
  int b = blockIdx.x, tid = threadIdx.x;
  float4 v;
  if (fbw != nullptr) {
    int id = idx_all[step * B_ + b];
    v.x = fbw[(size_t)(tid * 4 + 0) * CLS_ + id];
    v.y = fbw[(size_t)(tid * 4 + 1) * CLS_ + id];
    v.z = fbw[(size_t)(tid * 4 + 2) * CLS_ + id];
    v.w = fbw[(size_t)(tid * 4 + 3) * CLS_ + id];
    ((float4*)(hout + (size_t)b * DIM_))[tid] = v;
  } else {
    v = ((const float4*)(x + (size_t)b * DIM_))[tid];
  }
  float ss = v.x * v.x + v.y * v.y + v.z * v.z + v.w * v.w;
#pragma unroll
  for (int m = 32; m; m >>= 1) ss += __shfl_xor(ss, m);
  __shared__ float red[4];
  if ((tid & 63) == 0) red[tid >> 6] = ss;
  __syncthreads();
  float tot = red[0] + red[1] + red[2] + red[3];
  float denom = sqrtf(tot * (1.0f / DIM_) + 1e-8f);
  float4 gv = ((const float4*)g)[tid];
  float o[4] = { v.x * gv.x / denom, v.y * gv.y / denom,
                 v.z * gv.z / denom, v.w * gv.w / denom };
  f16x4 hv, lv;
#pragma unroll
  for (int j = 0; j < 4; ++j) { f16 hh, ll; split2(o[j], hh, ll); hv[j] = hh; lv[j] = ll; }
  *(f16x4*)(nh + (size_t)b * DIM_ + tid * 4) = hv;
  *(f16x4*)(nl + (size_t)b * DIM_ + tid * 4) = lv;
}

// ---------------- async staging via global_load_lds (width=16, linear LDS) ----------------
// LDS plane layout: granule (row, ksl) at byte (row*8+ksl)*16, holding GLOBAL k-slot
// ksl ^ (row&7). Instruction i covers granules i*64..i*64+63 = 8 rows x 128B
// contiguous global (fully coalesced). Reads address (r, ks^(r&7)) -> global (r,ks).
template<int R>
__device__ __forceinline__ void stage_async(const f16* __restrict__ gsrc,
    f16* lb, int K, int k0, int lane)
{
  const int row = (lane >> 3);         // row offset within 8-row group
  const int ksl = lane & 7;
#pragma unroll
  for (int i = 0; i < R / 8; ++i) {
    int r = i * 8 + row;
    int ksg = ksl ^ (r & 7);
    const f16* src = gsrc + (size_t)r * K + k0 + ksg * 8;
    __builtin_amdgcn_global_load_lds(
        (const __attribute__((address_space(1))) void*)src,
        (__attribute__((address_space(3))) void*)(lb + (size_t)i * 512),
        16, 0, 0);
  }
}

// ---------------- generic plane GEMM ----------------
// A planes [M][K] f16 hi/lo; B planes [N][K] f16 hi/lo; C fp32 [M][ldc].
// waves 2x2 over (BM/2, BN/2); mfma 16x16x32; 3 passes.
// LDS row-major granules with ks-XOR source pre-swizzle (coalesced + conflict-free).
// NOTE (r13 post-mortem): NO min-waves launch_bounds — natural VGPR use is >168,
// forcing 3 waves/EU spilled accumulators to scratch (6.2ms -> 16ms).
// NOTE (r16 post-mortem): grid-x MUST cover N/BN — ff1 launched at half N poisoned acth.
// EPI: 0=none, 1=C+=, 2=+bias X[col], 3=GLU (writes Oh/Ol planes),
//      4=QKV rope+scatter (C=qb fp32, KC/VC caches, T=step; needs BN>=64)
template<int BM, int BN, int EPI>
__global__ __launch_bounds__(256) void gemm_pl_k(
    const f16* __restrict__ Ah, const f16* __restrict__ Al,
    const f16* __restrict__ Bh, const f16* __restrict__ Bl,
    float* __restrict__ C, const float* __restrict__ X,
    f16* __restrict__ Oh, f16* __restrict__ Ol,
    float* __restrict__ KC, float* __restrict__ VC, int T,
    int K, int ldc)
{
  __shared__ f16 sAh[BM * 64];
  __shared__ f16 sAl[BM * 64];
  __shared__ f16 sBh[BN * 64];
  __shared__ f16 sBl[BN * 64];
  constexpr int MI = BM / 32, NI = BN / 32;
  const int tid  = threadIdx.x;
  const int lane = tid & 63, wid = tid >> 6;
  const int wr = wid >> 1, wc = wid & 1;
  const int bm = blockIdx.y * BM, bn = blockIdx.x * BN;
  const int fr = lane & 15, kq = lane >> 4;

  f32x4 acc0[MI][NI] = {}, acc1[MI][NI] = {};

  for (int k0 = 0; k0 < K; k0 += 64) {
    if      (wid == 0) stage_async<BM>(Ah + (size_t)bm * K, sAh, K, k0, lane);
    else if (wid == 1) stage_async<BM>(Al + (size_t)bm * K, sAl, K, k0, lane);
    else if (wid == 2) stage_async<BN>(Bh + (size_t)bn * K, sBh, K, k0, lane);
    else               stage_async<BN>(Bl + (size_t)bn * K, sBl, K, k0, lane);
    __syncthreads();
#pragma unroll
    for (int half = 0; half < 2; ++half) {
      const int ks = half * 4 + kq;
      f16x8 ah[MI], al[MI], bh[NI], bl[NI];
#pragma unroll
      for (int mi = 0; mi < MI; ++mi) {
        int r = wr * (BM / 2) + mi * 16 + fr;
        int idx = (r * 8 + (ks ^ (r & 7))) * 8;
        ah[mi] = *(const f16x8*)&sAh[idx];
        al[mi] = *(const f16x8*)&sAl[idx];
      }
#pragma unroll
      for (int ni = 0; ni < NI; ++ni) {
        int r = wc * (BN / 2) + ni * 16 + fr;
        int idx = (r * 8 + (ks ^ (r & 7))) * 8;
        bh[ni] = *(const f16x8*)&sBh[idx];
        bl[ni] = *(const f16x8*)&sBl[idx];
      }
#pragma unroll
      for (int mi = 0; mi < MI; ++mi)
#pragma unroll
        for (int ni = 0; ni < NI; ++ni) {
          acc0[mi][ni] = __builtin_amdgcn_mfma_f32_16x16x32_f16(ah[mi], bh[ni], acc0[mi][ni], 0, 0, 0);
          acc1[mi][ni] = __builtin_amdgcn_mfma_f32_16x16x32_f16(ah[mi], bl[ni], acc1[mi][ni], 0, 0, 0);
          acc1[mi][ni] = __builtin_amdgcn_mfma_f32_16x16x32_f16(al[mi], bh[ni], acc1[mi][ni], 0, 0, 0);
        }
    }
    __syncthreads();
  }

  // epilogue: C/D layout col=lane&15, row=(lane>>4)*4+reg
  if constexpr (EPI == 4) {
    // RoPE pairs are (2p, 2p+1) fragments (cols c, c+16) in the SAME lane.
    // Angle exactly as validated qkv_post_k (r6): powf + cosf/sinf.
    float invf = 1.0f / powf(10000.0f, (float)(2 * fr) * (1.0f / ROT_));
    float ang = (float)T * invf;
    float cs = cosf(ang), sn = sinf(ang);
    const int colbase = bn + wc * (BN / 2);
    const int sec = colbase >> 7;        // 0=q, 1=k, 2=v
    const int dbase = colbase & 127;
#pragma unroll
    for (int mi = 0; mi < MI; ++mi) {
#pragma unroll
      for (int r = 0; r < 4; ++r) {
        int b = bm + wr * (BM / 2) + mi * 16 + kq * 4 + r;
        float vv[NI];
#pragma unroll
        for (int ni = 0; ni < NI; ++ni)
          vv[ni] = acc0[mi][ni][r] + acc1[mi][ni][r] * SPLIT_INV;
        float* dst;
        if (sec == 0)      dst = C  + (size_t)b * INNER_ + dbase;
        else if (sec == 1) dst = KC + ((size_t)b * SEQ_ + T) * INNER_ + dbase;
        else               dst = VC + ((size_t)b * SEQ_ + T) * INNER_ + dbase;
#pragma unroll
        for (int p = 0; p < NI / 2; ++p) {
          bool rope = (sec < 2) && (((dbase + 32 * p) & 32) == 0);
          float v0 = vv[2 * p], v1 = vv[2 * p + 1];
          float o0 = rope ? (v0 * cs - v1 * sn) : v0;
          float o1 = rope ? (v1 * cs + v0 * sn) : v1;
          dst[(2 * p) * 16 + fr]     = o0;
          dst[(2 * p + 1) * 16 + fr] = o1;
        }
      }
    }
  } else {
#pragma unroll
    for (int mi = 0; mi < MI; ++mi) {
#pragma unroll
      for (int ni = 0; ni < NI; ++ni) {
        int colp = bn + wc * (BN / 2) + ni * 16 + fr;
#pragma unroll
        for (int r = 0; r < 4; ++r) {
          int row = bm + wr * (BM / 2) + mi * 16 + kq * 4 + r;
          float v = acc0[mi][ni][r] + acc1[mi][ni][r] * SPLIT_INV;
          if constexpr (EPI == 3) {
            float vg = __shfl_xor(v, 1);
            if ((fr & 1) == 0) {
              float act = v * gelu_tanh(vg);
              f16 hh, ll; split2(act, hh, ll);
              int oc = colp >> 1;
              Oh[(size_t)row * FFI_ + oc] = hh;
              Ol[(size_t)row * FFI_ + oc] = ll;
            }
          } else {
            if constexpr (EPI == 1) v += C[(size_t)row * ldc + colp];
            if constexpr (EPI == 2) v += X[colp];
            C[(size_t)row * ldc + colp] = v;
          }
        }
      }
    }
  }
}

// ---------------- attention (2 batches per 256-thread block) -> f16 planes ----------------
__global__ __launch_bounds__(256) void attn_k(
    const float* __restrict__ qb, const float* __restrict__ kc,
    const float* __restrict__ vc, f16* __restrict__ obh, f16* __restrict__ obl, int t)
{
  int b = blockIdx.x * 2 + (threadIdx.x >> 7);
  int h = (threadIdx.x >> 6) & 1, d = threadIdx.x & 63;
  float qd = qb[(size_t)b * INNER_ + h * DH_ + d];
  const float* kp = kc + (size_t)b * SEQ_ * INNER_ + h * DH_ + d;
  const float* vp = vc + (size_t)b * SEQ_ * INNER_ + h * DH_ + d;
  float s[SEQ_];
#pragma unroll
  for (int j = 0; j < SEQ_; ++j) {
    if (j <= t) {
      float p = qd * kp[j * INNER_];
#pragma unroll
      for (int m = 32; m; m >>= 1) p += __shfl_xor(p, m);
      s[j] = p * 0.125f;
    } else s[j] = -1e30f;
  }
  float mx = s[0];
#pragma unroll
  for (int j = 1; j < SEQ_; ++j) if (j <= t) mx = fmaxf(mx, s[j]);
  float sum = 0.0f;
#pragma unroll
  for (int j = 0; j < SEQ_; ++j) if (j <= t) { s[j] = expf(s[j] - mx); sum += s[j]; }
  float od = 0.0f;
#pragma unroll
  for (int j = 0; j < SEQ_; ++j) if (j <= t) od += (s[j] / sum) * vp[j * INNER_];
  f16 hh, ll; split2(od, hh, ll);
  obh[(size_t)b * INNER_ + h * DH_ + d] = hh;
  obl[(size_t)b * INNER_ + h * DH_ + d] = ll;
}

// ---------------- gumbel sample (partitionable threefry), used bitfield, segmented mp ----------------
__global__ __launch_bounds__(256) void sample_k(
    const float* __restrict__ logits, unsigned* __restrict__ usedw,
    float* __restrict__ mp, int* __restrict__ idx_all, float* __restrict__ codes_f,
    unsigned k0, unsigned k1, int step)
{
  int b = blockIdx.x, tid = threadIdx.x;
  float mk[4], val[4];
  int cs[4];
#pragma unroll
  for (int r = 0; r < 4; ++r) {
    int c = tid + r * 256;
    unsigned j = (unsigned)(b * CLS_ + c);
    unsigned x0 = 0u, x1 = j;
    tf2x32(k0, k1, x0, x1);
    unsigned bits = x0 ^ x1;
    float f = __uint_as_float((bits >> 9) | 0x3f800000u) - 1.0f;
    float u = fmaxf(f, 1.17549435e-38f);
    float gmb = (float)(-log(-log((double)u)));
    float lg = logits[(size_t)b * CLS_ + c];
    int isused = (usedw[(b * CLS_ + c) >> 5] >> (c & 31)) & 1;
    float m = isused ? -INFINITY : lg;
    mk[r] = m; val[r] = m + gmb; cs[r] = c;
  }
  float bv = val[0]; int bi = cs[0]; float bm = mk[0];
#pragma unroll
  for (int r = 1; r < 4; ++r) {
    if (val[r] > bv || (val[r] == bv && cs[r] < bi)) { bv = val[r]; bi = cs[r]; }
    bm = fmaxf(bm, mk[r]);
  }
#pragma unroll
  for (int m_ = 32; m_; m_ >>= 1) {
    float ov = __shfl_xor(bv, m_); int oi = __shfl_xor(bi, m_);
    if (ov > bv || (ov == bv && oi < bi)) { bv = ov; bi = oi; }
    bm = fmaxf(bm, __shfl_xor(bm, m_));
  }
  __shared__ float sv[4]; __shared__ int si[4]; __shared__ float sm_[4]; __shared__ float ssum[4];
  __shared__ int s_bidx; __shared__ float s_rowm; __shared__ float s_tot;
  int w = tid >> 6;
  if ((tid & 63) == 0) { sv[w] = bv; si[w] = bi; sm_[w] = bm; }
  __syncthreads();
  if (tid == 0) {
    float v = sv[0]; int ii = si[0]; float mm = sm_[0];
    for (int q = 1; q < 4; ++q) {
      if (sv[q] > v || (sv[q] == v && si[q] < ii)) { v = sv[q]; ii = si[q]; }
      mm = fmaxf(mm, sm_[q]);
    }
    s_bidx = ii; s_rowm = mm;
  }
  __syncthreads();
  float m2 = s_rowm;
  float pv[4]; float psum = 0.0f;
#pragma unroll
  for (int r = 0; r < 4; ++r) { pv[r] = expf(mk[r] - m2); psum += pv[r]; }
#pragma unroll
  for (int m_ = 32; m_; m_ >>= 1) psum += __shfl_xor(psum, m_);
  if ((tid & 63) == 0) ssum[w] = psum;
  __syncthreads();
  if (tid == 0) s_tot = ssum[0] + ssum[1] + ssum[2] + ssum[3];
  __syncthreads();
  float tot = s_tot;
  float* mpseg = mp + (size_t)(b & (NSEG_ - 1)) * CLS_;
#pragma unroll
  for (int r = 0; r < 4; ++r) atomicAdd(&mpseg[cs[r]], pv[r] / tot);
  if (tid == 0) {
    idx_all[step * B_ + b] = s_bidx;
    codes_f[step * B_ + b] = (float)s_bidx;
    usedw[(b * CLS_ + s_bidx) >> 5] |= 1u << (s_bidx & 31);
  }
}

// ---------------- perplexity accumulate (sums & zeroes the NSEG segments) ----------------
__global__ __launch_bounds__(256) void perp_k(float* __restrict__ mp, float* __restrict__ acc)
{
  int tid = threadIdx.x;
  float s = 0.0f;
#pragma unroll
  for (int r = 0; r < 4; ++r) {
    int c = tid + r * 256;
    float m = 0.0f;
    for (int seg = 0; seg < NSEG_; ++seg) {
      m += mp[(size_t)seg * CLS_ + c];
      mp[(size_t)seg * CLS_ + c] = 0.0f;
    }
    m *= (1.0f / (float)B_);
    s += m * logf(m + 1e-7f);
  }
#pragma unroll
  for (int m_ = 32; m_; m_ >>= 1) s += __shfl_xor(s, m_);
  __shared__ float red[4];
  if ((tid & 63) == 0) red[tid >> 6] = s;
  __syncthreads();
  if (tid == 0) *acc += expf(-(red[0] + red[1] + red[2] + red[3]));
}

// ---------------- results = cumsum of codebook columns (class 0 zeroed) + perp tail ----------------
__global__ __launch_bounds__(256) void results_k(
    const float* __restrict__ cbw, const int* __restrict__ idx_all,
    const float* __restrict__ perp, float* __restrict__ outp)
{
  int b = blockIdx.x, tid = threadIdx.x;
  float acc[4] = {0.f, 0.f, 0.f, 0.f};
  for (int s = 0; s < SEQ_; ++s) {
    int id = idx_all[s * B_ + b];
    if (id != 0) {
#pragma unroll
      for (int j = 0; j < 4; ++j)
        acc[j] += cbw[(size_t)(tid * 4 + j) * CLS_ + id];
    }
    float4 o = {acc[0], acc[1], acc[2], acc[3]};
    ((float4*)(outp + ((size_t)s * B_ + b) * ODIM_))[tid] = o;
  }
  if (b == 0 && tid == 0)
    outp[(size_t)SEQ_ * B_ * ODIM_] = perp[0] * (1.0f / (float)SEQ_);
}

// ---------------- transpose-split (z-batched over layers) ----------------
__global__ __launch_bounds__(256) void tsplit_k(const float* __restrict__ in,
    f16* __restrict__ oh, f16* __restrict__ ol,
    int ldin, int csrc0, int obase, int ostep, int ldo,
    size_t inLstr, size_t outLstr)
{
  int l = blockIdx.z;
  in += (size_t)l * inLstr;
  oh += (size_t)l * outLstr;
  ol += (size_t)l * outLstr;
  __shared__ float tile[32][33];
  int c0 = blockIdx.x * 32, r0 = blockIdx.y * 32;
  int tx = threadIdx.x & 31, ty = threadIdx.x >> 5;
  for (int i = 0; i < 32; i += 8)
    tile[ty + i][tx] = in[(size_t)(r0 + ty + i) * ldin + csrc0 + c0 + tx];
  __syncthreads();
  for (int i = 0; i < 32; i += 8) {
    int c = c0 + ty + i, r = r0 + tx;
    float v = tile[tx][ty + i];
    f16 hh, ll; split2(v, hh, ll);
    size_t orow = (size_t)obase + (size_t)ostep * c;
    oh[orow * ldo + r] = hh;
    ol[orow * ldo + r] = ll;
  }
}

// ---------------- elementwise split (cls_w already [N][K]) ----------------
__global__ __launch_bounds__(256) void esplit_k(const float* __restrict__ in,
    f16* __restrict__ oh, f16* __restrict__ ol)
{
  int i = blockIdx.x * 1024 + threadIdx.x * 4;
  float4 v = *(const float4*)(in + i);
  f16x4 hv, lv;
  float a[4] = {v.x, v.y, v.z, v.w};
#pragma unroll
  for (int j = 0; j < 4; ++j) { f16 hh, ll; split2(a[j], hh, ll); hv[j] = hh; lv[j] = ll; }
  *(f16x4*)(oh + i) = hv;
  *(f16x4*)(ol + i) = lv;
}

extern "C" void kernel_launch(void* const* d_in, const int* in_sizes, int n_in,
                              void* d_out, int out_size, void* d_ws, size_t ws_size,
                              hipStream_t stream)
{
  const float* x       = (const float*)d_in[0];
  const float* rms1_g  = (const float*)d_in[1];
  const float* wq      = (const float*)d_in[2];
  const float* wk      = (const float*)d_in[3];
  const float* wv      = (const float*)d_in[4];
  const float* wo      = (const float*)d_in[5];
  const float* rms2_g  = (const float*)d_in[6];
  const float* ff_w1   = (const float*)d_in[7];
  const float* ff_w2   = (const float*)d_in[8];
  const float* final_g = (const float*)d_in[9];
  const float* cls_w   = (const float*)d_in[10];
  const float* cls_b   = (const float*)d_in[11];
  const float* fb_w    = (const float*)d_in[12];
  const float* cb_w    = (const float*)d_in[13];
  float* outp = (float*)d_out;

  char* base = (char*)d_ws;
  size_t off = 0;
  auto alloc = [&](size_t bytes) -> void* {
    void* p = base + off;
    off = (off + bytes + 255) & ~(size_t)255;
    return p;
  };
  // ---- base scratch (~114 MB, proven-safe) ----
  float* kcache = (float*)alloc((size_t)DEPTH_ * B_ * SEQ_ * INNER_ * 4);
  float* vcache = (float*)alloc((size_t)DEPTH_ * B_ * SEQ_ * INNER_ * 4);
  float* h      = (float*)alloc((size_t)B_ * DIM_ * 4);
  f16*   nh     = (f16*)alloc((size_t)B_ * DIM_ * 2);
  f16*   nl     = (f16*)alloc((size_t)B_ * DIM_ * 2);
  char*  arena  = (char*)alloc((size_t)B_ * FFI_ * 2 * 2);   // 16.78 MB union
  unsigned* usedw = (unsigned*)alloc((size_t)B_ * CLS_ / 8);
  int*   idx_all= (int*)alloc((size_t)SEQ_ * B_ * 4);
  float* mp     = (float*)alloc((size_t)NSEG_ * CLS_ * 4);   // segmented histogram
  float* perp   = (float*)alloc(256);
  f16* W3h  = (f16*)alloc((size_t)DEPTH_ * 384 * DIM_ * 2);
  f16* W3l  = (f16*)alloc((size_t)DEPTH_ * 384 * DIM_ * 2);
  f16* woh  = (f16*)alloc((size_t)DEPTH_ * DIM_ * INNER_ * 2);
  f16* wol  = (f16*)alloc((size_t)DEPTH_ * DIM_ * INNER_ * 2);
  f16* clsh = (f16*)alloc((size_t)CLS_ * DIM_ * 2);
  f16* clsl = (f16*)alloc((size_t)CLS_ * DIM_ * 2);
  if (off > ws_size) return;

  // arena members (lifetime-disjoint within a layer/step)
  f16*   acth = (f16*)arena;
  f16*   actl = acth + (size_t)B_ * FFI_;
  float* qb   = (float*)arena;
  f16*   obh  = (f16*)(qb + (size_t)B_ * INNER_);
  f16*   obl  = obh + (size_t)B_ * INNER_;
  float* logits = (float*)arena;

  // ---- adaptive tiers ----
  const size_t ff2_bytes = (size_t)DEPTH_ * DIM_ * FFI_ * 2;
  const size_t ff1_bytes = (size_t)DEPTH_ * 2 * FFI_ * DIM_ * 2;
  bool ff2pl = (off + 2 * ff2_bytes <= ws_size);
  f16 *ff2h = nullptr, *ff2l = nullptr;
  if (ff2pl) { ff2h = (f16*)alloc(ff2_bytes); ff2l = (f16*)alloc(ff2_bytes); }
  bool ff1ws = ff2pl && (off + 2 * ff1_bytes <= ws_size);
  f16 *ff1h, *ff1l;
  if (ff1ws) { ff1h = (f16*)alloc(ff1_bytes); ff1l = (f16*)alloc(ff1_bytes); }
  else {
    ff1h = (f16*)outp;                         // d_out scratch (proven r6-r15)
    ff1l = (f16*)((char*)d_out + ff1_bytes);
  }

  unsigned key0[SEQ_], key1[SEQ_];
  for (int i = 0; i < SEQ_; ++i) {
    unsigned a = 0u, b = (unsigned)i;
    tf2x32(0u, 42u, a, b);
    key0[i] = a; key1[i] = b;
  }

  hipMemsetAsync(usedw, 0, (size_t)B_ * CLS_ / 8, stream);
  hipMemsetAsync(mp, 0, (size_t)NSEG_ * CLS_ * 4, stream);
  hipMemsetAsync(perp, 0, 4, stream);

  // ---- build weight planes (z-batched over layers) ----
  tsplit_k<<<dim3(4, 32, DEPTH_), 256, 0, stream>>>(wq, W3h, W3l, 128, 0, 0,   1, DIM_, (size_t)DIM_ * 128, (size_t)384 * DIM_);
  tsplit_k<<<dim3(4, 32, DEPTH_), 256, 0, stream>>>(wk, W3h, W3l, 128, 0, 128, 1, DIM_, (size_t)DIM_ * 128, (size_t)384 * DIM_);
  tsplit_k<<<dim3(4, 32, DEPTH_), 256, 0, stream>>>(wv, W3h, W3l, 128, 0, 256, 1, DIM_, (size_t)DIM_ * 128, (size_t)384 * DIM_);
  tsplit_k<<<dim3(32, 4, DEPTH_), 256, 0, stream>>>(wo, woh, wol, DIM_, 0, 0, 1, INNER_, (size_t)INNER_ * DIM_, (size_t)DIM_ * INNER_);
  tsplit_k<<<dim3(64, 32, DEPTH_), 256, 0, stream>>>(ff_w1, ff1h, ff1l, 2 * FFI_, 0,    0, 2, DIM_, (size_t)DIM_ * 2 * FFI_, (size_t)2 * FFI_ * DIM_);
  tsplit_k<<<dim3(64, 32, DEPTH_), 256, 0, stream>>>(ff_w1, ff1h, ff1l, 2 * FFI_, FFI_, 1, 2, DIM_, (size_t)DIM_ * 2 * FFI_, (size_t)2 * FFI_ * DIM_);
  if (ff2pl)
    tsplit_k<<<dim3(32, 64, DEPTH_), 256, 0, stream>>>(ff_w2, ff2h, ff2l, DIM_, 0, 0, 1, FFI_, (size_t)FFI_ * DIM_, (size_t)DIM_ * FFI_);
  esplit_k<<<(CLS_ * DIM_) / 1024, 256, 0, stream>>>(cls_w, clsh, clsl);
  hipMemcpyAsync(h, x, (size_t)B_ * DIM_ * 4, hipMemcpyDeviceToDevice, stream);

  float* codes_f = outp + (size_t)SEQ_ * B_ * ODIM_ + 1;

  for (int t = 0; t < SEQ_; ++t) {
    for (int l = 0; l < DEPTH_; ++l) {
      float* kc = kcache + (size_t)l * B_ * SEQ_ * INNER_;
      float* vc = vcache + (size_t)l * B_ * SEQ_ * INNER_;
      if (l == 0 && t > 0)
        rmsnorm_split_k<<<B_, 256, 0, stream>>>(nullptr, rms1_g + (size_t)l * DIM_, nh, nl, h, fb_w, idx_all, t - 1);
      else
        rmsnorm_split_k<<<B_, 256, 0, stream>>>(h, rms1_g + (size_t)l * DIM_, nh, nl, nullptr, nullptr, nullptr, 0);
      gemm_pl_k<32, 64, 4><<<dim3(6, 64), 256, 0, stream>>>(nh, nl,
          W3h + (size_t)l * 384 * DIM_, W3l + (size_t)l * 384 * DIM_,
          qb, nullptr, nullptr, nullptr, kc, vc, t, DIM_, 0);
      attn_k<<<B_ / 2, 256, 0, stream>>>(qb, kc, vc, obh, obl, t);
      gemm_pl_k<32, 64, 1><<<dim3(16, 64), 256, 0, stream>>>(obh, obl,
          woh + (size_t)l * DIM_ * INNER_, wol + (size_t)l * DIM_ * INNER_,
          h, nullptr, nullptr, nullptr, nullptr, nullptr, 0, INNER_, DIM_);
      rmsnorm_split_k<<<B_, 256, 0, stream>>>(h, rms2_g + (size_t)l * DIM_, nh, nl, nullptr, nullptr, nullptr, 0);
      gemm_pl_k<32, 128, 3><<<dim3(32, 64), 256, 0, stream>>>(nh, nl,
          ff1h + (size_t)l * 2 * FFI_ * DIM_, ff1l + (size_t)l * 2 * FFI_ * DIM_,
          nullptr, nullptr, acth, actl, nullptr, nullptr, 0, DIM_, 0);
      if (ff2pl) {
        gemm_pl_k<32, 64, 1><<<dim3(16, 64), 256, 0, stream>>>(acth, actl,
            ff2h + (size_t)l * DIM_ * FFI_, ff2l + (size_t)l * DIM_ * FFI_,
            h, nullptr, nullptr, nullptr, nullptr, nullptr, 0, FFI_, DIM_);
      } else {
        tsplit_k<<<dim3(32, 64, 1), 256, 0, stream>>>(ff_w2 + (size_t)l * FFI_ * DIM_,
            nh, nl, DIM_, 0, 0, 1, FFI_, 0, 0);
        gemm_pl_k<32, 64, 1><<<dim3(16, 64), 256, 0, stream>>>(acth, actl,
            nh, nl, h, nullptr, nullptr, nullptr, nullptr, nullptr, 0, FFI_, DIM_);
      }
    }
    rmsnorm_split_k<<<B_, 256, 0, stream>>>(h, final_g, nh, nl, nullptr, nullptr, nullptr, 0);
    gemm_pl_k<32, 64, 2><<<dim3(16, 64), 256, 0, stream>>>(nh, nl,
        clsh, clsl, logits, cls_b, nullptr, nullptr, nullptr, nullptr, 0, DIM_, CLS_);
    sample_k<<<B_, 256, 0, stream>>>(logits, usedw, mp, idx_all, codes_f, key0[t], key1[t], t);
    perp_k<<<1, 256, 0, stream>>>(mp, perp);
  }

  results_k<<<B_, 256, 0, stream>>>(cb_w, idx_all, perp, outp);
}

// Round 18
// 5332.603 us; speedup vs baseline: 1.1140x; 1.1140x over previous
//
#include <hip/hip_runtime.h>
#include <hip/hip_bf16.h>

#define B_     2048
#define DIM_   1024
#define CLS_   1024
#define ODIM_  1024
#define DEPTH_ 4
#define SEQ_   8
#define INNER_ 128
#define DH_    64
#define FFI_   2048
#define ROT_   32
#define NSEG_  64

typedef _Float16 f16;
typedef f16 f16x4 __attribute__((ext_vector_type(4)));
typedef f16 f16x8 __attribute__((ext_vector_type(8)));
typedef float f32x4 __attribute__((ext_vector_type(4)));

#define SPLIT_SCALE 2048.0f
#define SPLIT_INV   (1.0f / 2048.0f)

__device__ __forceinline__ void split2(float x, f16& h, f16& l) {
  f16 hh = (f16)x;
  h = hh;
  l = (f16)((x - (float)hh) * SPLIT_SCALE);
}

// ---------------- threefry2x32 (matches jax._src.prng, 20 rounds) ----------------
__host__ __device__ inline void tf2x32(unsigned k0, unsigned k1, unsigned& x0, unsigned& x1)
{
  unsigned ks2 = k0 ^ k1 ^ 0x1BD11BDAu;
  x0 += k0; x1 += k1;
#define TFR(r) { x0 += x1; x1 = (x1 << (r)) | (x1 >> (32 - (r))); x1 ^= x0; }
  TFR(13) TFR(15) TFR(26) TFR(6)
  x0 += k1;  x1 += ks2 + 1u;
  TFR(17) TFR(29) TFR(16) TFR(24)
  x0 += ks2; x1 += k0 + 2u;
  TFR(13) TFR(15) TFR(26) TFR(6)
  x0 += k0;  x1 += k1 + 3u;
  TFR(17) TFR(29) TFR(16) TFR(24)
  x0 += k1;  x1 += ks2 + 4u;
  TFR(13) TFR(15) TFR(26) TFR(6)
  x0 += ks2; x1 += k0 + 5u;
#undef TFR
}

__device__ inline float gelu_tanh(float x) {
  float t = tanhf(0.7978845608028654f * (x + 0.044715f * (x * x * x)));
  return x * 0.5f * (1.0f + t);
}

// ---------------- rmsnorm (+optional fused feedback gather) -> f16 planes ----------------
__global__ __launch_bounds__(256) void rmsnorm_split_k(const float* __restrict__ x,
    const float* __restrict__ g, f16* __restrict__ nh, f16* __restrict__ nl,
    float* __restrict__ hout, const float* __restrict__ fbw,
    const int* __restrict__ idx_all, int step)
{
  int b = blockIdx.x, tid = threadIdx.x;
  float4 v;
  if (fbw != nullptr) {
    int id = idx_all[step * B_ + b];
    v.x = fbw[(size_t)(tid * 4 + 0) * CLS_ + id];
    v.y = fbw[(size_t)(tid * 4 + 1) * CLS_ + id];
    v.z = fbw[(size_t)(tid * 4 + 2) * CLS_ + id];
    v.w = fbw[(size_t)(tid * 4 + 3) * CLS_ + id];
    ((float4*)(hout + (size_t)b * DIM_))[tid] = v;
  } else {
    v = ((const float4*)(x + (size_t)b * DIM_))[tid];
  }
  float ss = v.x * v.x + v.y * v.y + v.z * v.z + v.w * v.w;
#pragma unroll
  for (int m = 32; m; m >>= 1) ss += __shfl_xor(ss, m);
  __shared__ float red[4];
  if ((tid & 63) == 0) red[tid >> 6] = ss;
  __syncthreads();
  float tot = red[0] + red[1] + red[2] + red[3];
  float denom = sqrtf(tot * (1.0f / DIM_) + 1e-8f);
  float4 gv = ((const float4*)g)[tid];
  float o[4] = { v.x * gv.x / denom, v.y * gv.y / denom,
                 v.z * gv.z / denom, v.w * gv.w / denom };
  f16x4 hv, lv;
#pragma unroll
  for (int j = 0; j < 4; ++j) { f16 hh, ll; split2(o[j], hh, ll); hv[j] = hh; lv[j] = ll; }
  *(f16x4*)(nh + (size_t)b * DIM_ + tid * 4) = hv;
  *(f16x4*)(nl + (size_t)b * DIM_ + tid * 4) = lv;
}

// ---------------- async staging via global_load_lds (width=16, linear LDS) ----------------
// LDS plane layout: granule (row, ksl) at byte (row*8+ksl)*16, holding GLOBAL k-slot
// ksl ^ (row&7). Instruction i covers granules i*64..i*64+63 = 8 rows x 128B
// contiguous global (fully coalesced). Reads address (r, ks^(r&7)) -> global (r,ks).
template<int R>
__device__ __forceinline__ void stage_async(const f16* __restrict__ gsrc,
    f16* lb, int K, int k0, int lane)
{
  const int row = (lane >> 3);         // row offset within 8-row group
  const int ksl = lane & 7;
#pragma unroll
  for (int i = 0; i < R / 8; ++i) {
    int r = i * 8 + row;
    int ksg = ksl ^ (r & 7);
    const f16* src = gsrc + (size_t)r * K + k0 + ksg * 8;
    __builtin_amdgcn_global_load_lds(
        (const __attribute__((address_space(1))) void*)src,
        (__attribute__((address_space(3))) void*)(lb + (size_t)i * 512),
        16, 0, 0);
  }
}

// ---------------- generic plane GEMM ----------------
// A planes [M][K] f16 hi/lo; B planes [N][K] f16 hi/lo; C fp32 [M][ldc].
// waves 2x2 over (BM/2, BN/2); mfma 16x16x32; 3 passes.
// LDS row-major granules with ks-XOR source pre-swizzle (coalesced + conflict-free).
// NOTE (r13): NO min-waves launch_bounds (VGPR >168 -> spills, 2.6x regression).
// NOTE (r16): grid-x MUST cover N/BN.
// NOTE (r17): 32-row tiles double B-staging traffic — 64-row tiles are the optimum.
// EPI: 0=none, 1=C+=, 2=+bias X[col], 3=GLU (writes Oh/Ol planes),
//      4=QKV rope+scatter (C=qb fp32, KC/VC caches, T=step; needs BN>=64)
template<int BM, int BN, int EPI>
__global__ __launch_bounds__(256) void gemm_pl_k(
    const f16* __restrict__ Ah, const f16* __restrict__ Al,
    const f16* __restrict__ Bh, const f16* __restrict__ Bl,
    float* __restrict__ C, const float* __restrict__ X,
    f16* __restrict__ Oh, f16* __restrict__ Ol,
    float* __restrict__ KC, float* __restrict__ VC, int T,
    int K, int ldc)
{
  __shared__ f16 sAh[BM * 64];
  __shared__ f16 sAl[BM * 64];
  __shared__ f16 sBh[BN * 64];
  __shared__ f16 sBl[BN * 64];
  constexpr int MI = BM / 32, NI = BN / 32;
  const int tid  = threadIdx.x;
  const int lane = tid & 63, wid = tid >> 6;
  const int wr = wid >> 1, wc = wid & 1;
  const int bm = blockIdx.y * BM, bn = blockIdx.x * BN;
  const int fr = lane & 15, kq = lane >> 4;

  f32x4 acc0[MI][NI] = {}, acc1[MI][NI] = {};

  for (int k0 = 0; k0 < K; k0 += 64) {
    if      (wid == 0) stage_async<BM>(Ah + (size_t)bm * K, sAh, K, k0, lane);
    else if (wid == 1) stage_async<BM>(Al + (size_t)bm * K, sAl, K, k0, lane);
    else if (wid == 2) stage_async<BN>(Bh + (size_t)bn * K, sBh, K, k0, lane);
    else               stage_async<BN>(Bl + (size_t)bn * K, sBl, K, k0, lane);
    __syncthreads();
#pragma unroll
    for (int half = 0; half < 2; ++half) {
      const int ks = half * 4 + kq;
      f16x8 ah[MI], al[MI], bh[NI], bl[NI];
#pragma unroll
      for (int mi = 0; mi < MI; ++mi) {
        int r = wr * (BM / 2) + mi * 16 + fr;
        int idx = (r * 8 + (ks ^ (r & 7))) * 8;
        ah[mi] = *(const f16x8*)&sAh[idx];
        al[mi] = *(const f16x8*)&sAl[idx];
      }
#pragma unroll
      for (int ni = 0; ni < NI; ++ni) {
        int r = wc * (BN / 2) + ni * 16 + fr;
        int idx = (r * 8 + (ks ^ (r & 7))) * 8;
        bh[ni] = *(const f16x8*)&sBh[idx];
        bl[ni] = *(const f16x8*)&sBl[idx];
      }
#pragma unroll
      for (int mi = 0; mi < MI; ++mi)
#pragma unroll
        for (int ni = 0; ni < NI; ++ni) {
          acc0[mi][ni] = __builtin_amdgcn_mfma_f32_16x16x32_f16(ah[mi], bh[ni], acc0[mi][ni], 0, 0, 0);
          acc1[mi][ni] = __builtin_amdgcn_mfma_f32_16x16x32_f16(ah[mi], bl[ni], acc1[mi][ni], 0, 0, 0);
          acc1[mi][ni] = __builtin_amdgcn_mfma_f32_16x16x32_f16(al[mi], bh[ni], acc1[mi][ni], 0, 0, 0);
        }
    }
    __syncthreads();
  }

  // epilogue: C/D layout col=lane&15, row=(lane>>4)*4+reg
  if constexpr (EPI == 4) {
    // RoPE pairs are (2p, 2p+1) fragments (cols c, c+16) in the SAME lane.
    // Angle exactly as validated qkv_post_k (r6): powf + cosf/sinf.
    float invf = 1.0f / powf(10000.0f, (float)(2 * fr) * (1.0f / ROT_));
    float ang = (float)T * invf;
    float cs = cosf(ang), sn = sinf(ang);
    const int colbase = bn + wc * (BN / 2);
    const int sec = colbase >> 7;        // 0=q, 1=k, 2=v
    const int dbase = colbase & 127;
#pragma unroll
    for (int mi = 0; mi < MI; ++mi) {
#pragma unroll
      for (int r = 0; r < 4; ++r) {
        int b = bm + wr * (BM / 2) + mi * 16 + kq * 4 + r;
        float vv[NI];
#pragma unroll
        for (int ni = 0; ni < NI; ++ni)
          vv[ni] = acc0[mi][ni][r] + acc1[mi][ni][r] * SPLIT_INV;
        float* dst;
        if (sec == 0)      dst = C  + (size_t)b * INNER_ + dbase;
        else if (sec == 1) dst = KC + ((size_t)b * SEQ_ + T) * INNER_ + dbase;
        else               dst = VC + ((size_t)b * SEQ_ + T) * INNER_ + dbase;
#pragma unroll
        for (int p = 0; p < NI / 2; ++p) {
          bool rope = (sec < 2) && (((dbase + 32 * p) & 32) == 0);
          float v0 = vv[2 * p], v1 = vv[2 * p + 1];
          float o0 = rope ? (v0 * cs - v1 * sn) : v0;
          float o1 = rope ? (v1 * cs + v0 * sn) : v1;
          dst[(2 * p) * 16 + fr]     = o0;
          dst[(2 * p + 1) * 16 + fr] = o1;
        }
      }
    }
  } else {
#pragma unroll
    for (int mi = 0; mi < MI; ++mi) {
#pragma unroll
      for (int ni = 0; ni < NI; ++ni) {
        int colp = bn + wc * (BN / 2) + ni * 16 + fr;
#pragma unroll
        for (int r = 0; r < 4; ++r) {
          int row = bm + wr * (BM / 2) + mi * 16 + kq * 4 + r;
          float v = acc0[mi][ni][r] + acc1[mi][ni][r] * SPLIT_INV;
          if constexpr (EPI == 3) {
            float vg = __shfl_xor(v, 1);
            if ((fr & 1) == 0) {
              float act = v * gelu_tanh(vg);
              f16 hh, ll; split2(act, hh, ll);
              int oc = colp >> 1;
              Oh[(size_t)row * FFI_ + oc] = hh;
              Ol[(size_t)row * FFI_ + oc] = ll;
            }
          } else {
            if constexpr (EPI == 1) v += C[(size_t)row * ldc + colp];
            if constexpr (EPI == 2) v += X[colp];
            C[(size_t)row * ldc + colp] = v;
          }
        }
      }
    }
  }
}

// ---------------- attention (2 batches per 256-thread block) -> f16 planes ----------------
__global__ __launch_bounds__(256) void attn_k(
    const float* __restrict__ qb, const float* __restrict__ kc,
    const float* __restrict__ vc, f16* __restrict__ obh, f16* __restrict__ obl, int t)
{
  int b = blockIdx.x * 2 + (threadIdx.x >> 7);
  int h = (threadIdx.x >> 6) & 1, d = threadIdx.x & 63;
  float qd = qb[(size_t)b * INNER_ + h * DH_ + d];
  const float* kp = kc + (size_t)b * SEQ_ * INNER_ + h * DH_ + d;
  const float* vp = vc + (size_t)b * SEQ_ * INNER_ + h * DH_ + d;
  float s[SEQ_];
#pragma unroll
  for (int j = 0; j < SEQ_; ++j) {
    if (j <= t) {
      float p = qd * kp[j * INNER_];
#pragma unroll
      for (int m = 32; m; m >>= 1) p += __shfl_xor(p, m);
      s[j] = p * 0.125f;
    } else s[j] = -1e30f;
  }
  float mx = s[0];
#pragma unroll
  for (int j = 1; j < SEQ_; ++j) if (j <= t) mx = fmaxf(mx, s[j]);
  float sum = 0.0f;
#pragma unroll
  for (int j = 0; j < SEQ_; ++j) if (j <= t) { s[j] = expf(s[j] - mx); sum += s[j]; }
  float od = 0.0f;
#pragma unroll
  for (int j = 0; j < SEQ_; ++j) if (j <= t) od += (s[j] / sum) * vp[j * INNER_];
  f16 hh, ll; split2(od, hh, ll);
  obh[(size_t)b * INNER_ + h * DH_ + d] = hh;
  obl[(size_t)b * INNER_ + h * DH_ + d] = ll;
}

// ---------------- gumbel sample (partitionable threefry), used bitfield, segmented mp ----------------
__global__ __launch_bounds__(256) void sample_k(
    const float* __restrict__ logits, unsigned* __restrict__ usedw,
    float* __restrict__ mp, int* __restrict__ idx_all, float* __restrict__ codes_f,
    unsigned k0, unsigned k1, int step)
{
  int b = blockIdx.x, tid = threadIdx.x;
  float mk[4], val[4];
  int cs[4];
#pragma unroll
  for (int r = 0; r < 4; ++r) {
    int c = tid + r * 256;
    unsigned j = (unsigned)(b * CLS_ + c);
    unsigned x0 = 0u, x1 = j;
    tf2x32(k0, k1, x0, x1);
    unsigned bits = x0 ^ x1;
    float f = __uint_as_float((bits >> 9) | 0x3f800000u) - 1.0f;
    float u = fmaxf(f, 1.17549435e-38f);
    float gmb = (float)(-log(-log((double)u)));
    float lg = logits[(size_t)b * CLS_ + c];
    int isused = (usedw[(b * CLS_ + c) >> 5] >> (c & 31)) & 1;
    float m = isused ? -INFINITY : lg;
    mk[r] = m; val[r] = m + gmb; cs[r] = c;
  }
  float bv = val[0]; int bi = cs[0]; float bm = mk[0];
#pragma unroll
  for (int r = 1; r < 4; ++r) {
    if (val[r] > bv || (val[r] == bv && cs[r] < bi)) { bv = val[r]; bi = cs[r]; }
    bm = fmaxf(bm, mk[r]);
  }
#pragma unroll
  for (int m_ = 32; m_; m_ >>= 1) {
    float ov = __shfl_xor(bv, m_); int oi = __shfl_xor(bi, m_);
    if (ov > bv || (ov == bv && oi < bi)) { bv = ov; bi = oi; }
    bm = fmaxf(bm, __shfl_xor(bm, m_));
  }
  __shared__ float sv[4]; __shared__ int si[4]; __shared__ float sm_[4]; __shared__ float ssum[4];
  __shared__ int s_bidx; __shared__ float s_rowm; __shared__ float s_tot;
  int w = tid >> 6;
  if ((tid & 63) == 0) { sv[w] = bv; si[w] = bi; sm_[w] = bm; }
  __syncthreads();
  if (tid == 0) {
    float v = sv[0]; int ii = si[0]; float mm = sm_[0];
    for (int q = 1; q < 4; ++q) {
      if (sv[q] > v || (sv[q] == v && si[q] < ii)) { v = sv[q]; ii = si[q]; }
      mm = fmaxf(mm, sm_[q]);
    }
    s_bidx = ii; s_rowm = mm;
  }
  __syncthreads();
  float m2 = s_rowm;
  float pv[4]; float psum = 0.0f;
#pragma unroll
  for (int r = 0; r < 4; ++r) { pv[r] = expf(mk[r] - m2); psum += pv[r]; }
#pragma unroll
  for (int m_ = 32; m_; m_ >>= 1) psum += __shfl_xor(psum, m_);
  if ((tid & 63) == 0) ssum[w] = psum;
  __syncthreads();
  if (tid == 0) s_tot = ssum[0] + ssum[1] + ssum[2] + ssum[3];
  __syncthreads();
  float tot = s_tot;
  float* mpseg = mp + (size_t)(b & (NSEG_ - 1)) * CLS_;
#pragma unroll
  for (int r = 0; r < 4; ++r) atomicAdd(&mpseg[cs[r]], pv[r] / tot);
  if (tid == 0) {
    idx_all[step * B_ + b] = s_bidx;
    codes_f[step * B_ + b] = (float)s_bidx;
    usedw[(b * CLS_ + s_bidx) >> 5] |= 1u << (s_bidx & 31);
  }
}

// ---------------- perplexity accumulate (sums & zeroes the NSEG segments) ----------------
__global__ __launch_bounds__(256) void perp_k(float* __restrict__ mp, float* __restrict__ acc)
{
  int tid = threadIdx.x;
  float s = 0.0f;
#pragma unroll
  for (int r = 0; r < 4; ++r) {
    int c = tid + r * 256;
    float m = 0.0f;
    for (int seg = 0; seg < NSEG_; ++seg) {
      m += mp[(size_t)seg * CLS_ + c];
      mp[(size_t)seg * CLS_ + c] = 0.0f;
    }
    m *= (1.0f / (float)B_);
    s += m * logf(m + 1e-7f);
  }
#pragma unroll
  for (int m_ = 32; m_; m_ >>= 1) s += __shfl_xor(s, m_);
  __shared__ float red[4];
  if ((tid & 63) == 0) red[tid >> 6] = s;
  __syncthreads();
  if (tid == 0) *acc += expf(-(red[0] + red[1] + red[2] + red[3]));
}

// ---------------- results = cumsum of codebook columns (class 0 zeroed) + perp tail ----------------
__global__ __launch_bounds__(256) void results_k(
    const float* __restrict__ cbw, const int* __restrict__ idx_all,
    const float* __restrict__ perp, float* __restrict__ outp)
{
  int b = blockIdx.x, tid = threadIdx.x;
  float acc[4] = {0.f, 0.f, 0.f, 0.f};
  for (int s = 0; s < SEQ_; ++s) {
    int id = idx_all[s * B_ + b];
    if (id != 0) {
#pragma unroll
      for (int j = 0; j < 4; ++j)
        acc[j] += cbw[(size_t)(tid * 4 + j) * CLS_ + id];
    }
    float4 o = {acc[0], acc[1], acc[2], acc[3]};
    ((float4*)(outp + ((size_t)s * B_ + b) * ODIM_))[tid] = o;
  }
  if (b == 0 && tid == 0)
    outp[(size_t)SEQ_ * B_ * ODIM_] = perp[0] * (1.0f / (float)SEQ_);
}

// ---------------- transpose-split (z-batched over layers) ----------------
__global__ __launch_bounds__(256) void tsplit_k(const float* __restrict__ in,
    f16* __restrict__ oh, f16* __restrict__ ol,
    int ldin, int csrc0, int obase, int ostep, int ldo,
    size_t inLstr, size_t outLstr)
{
  int l = blockIdx.z;
  in += (size_t)l * inLstr;
  oh += (size_t)l * outLstr;
  ol += (size_t)l * outLstr;
  __shared__ float tile[32][33];
  int c0 = blockIdx.x * 32, r0 = blockIdx.y * 32;
  int tx = threadIdx.x & 31, ty = threadIdx.x >> 5;
  for (int i = 0; i < 32; i += 8)
    tile[ty + i][tx] = in[(size_t)(r0 + ty + i) * ldin + csrc0 + c0 + tx];
  __syncthreads();
  for (int i = 0; i < 32; i += 8) {
    int c = c0 + ty + i, r = r0 + tx;
    float v = tile[tx][ty + i];
    f16 hh, ll; split2(v, hh, ll);
    size_t orow = (size_t)obase + (size_t)ostep * c;
    oh[orow * ldo + r] = hh;
    ol[orow * ldo + r] = ll;
  }
}

// ---------------- elementwise split (cls_w already [N][K]) ----------------
__global__ __launch_bounds__(256) void esplit_k(const float* __restrict__ in,
    f16* __restrict__ oh, f16* __restrict__ ol)
{
  int i = blockIdx.x * 1024 + threadIdx.x * 4;
  float4 v = *(const float4*)(in + i);
  f16x4 hv, lv;
  float a[4] = {v.x, v.y, v.z, v.w};
#pragma unroll
  for (int j = 0; j < 4; ++j) { f16 hh, ll; split2(a[j], hh, ll); hv[j] = hh; lv[j] = ll; }
  *(f16x4*)(oh + i) = hv;
  *(f16x4*)(ol + i) = lv;
}

extern "C" void kernel_launch(void* const* d_in, const int* in_sizes, int n_in,
                              void* d_out, int out_size, void* d_ws, size_t ws_size,
                              hipStream_t stream)
{
  const float* x       = (const float*)d_in[0];
  const float* rms1_g  = (const float*)d_in[1];
  const float* wq      = (const float*)d_in[2];
  const float* wk      = (const float*)d_in[3];
  const float* wv      = (const float*)d_in[4];
  const float* wo      = (const float*)d_in[5];
  const float* rms2_g  = (const float*)d_in[6];
  const float* ff_w1   = (const float*)d_in[7];
  const float* ff_w2   = (const float*)d_in[8];
  const float* final_g = (const float*)d_in[9];
  const float* cls_w   = (const float*)d_in[10];
  const float* cls_b   = (const float*)d_in[11];
  const float* fb_w    = (const float*)d_in[12];
  const float* cb_w    = (const float*)d_in[13];
  float* outp = (float*)d_out;

  char* base = (char*)d_ws;
  size_t off = 0;
  auto alloc = [&](size_t bytes) -> void* {
    void* p = base + off;
    off = (off + bytes + 255) & ~(size_t)255;
    return p;
  };
  // ---- base scratch (~114 MB, proven-safe) ----
  float* kcache = (float*)alloc((size_t)DEPTH_ * B_ * SEQ_ * INNER_ * 4);
  float* vcache = (float*)alloc((size_t)DEPTH_ * B_ * SEQ_ * INNER_ * 4);
  float* h      = (float*)alloc((size_t)B_ * DIM_ * 4);
  f16*   nh     = (f16*)alloc((size_t)B_ * DIM_ * 2);
  f16*   nl     = (f16*)alloc((size_t)B_ * DIM_ * 2);
  char*  arena  = (char*)alloc((size_t)B_ * FFI_ * 2 * 2);   // 16.78 MB union
  unsigned* usedw = (unsigned*)alloc((size_t)B_ * CLS_ / 8);
  int*   idx_all= (int*)alloc((size_t)SEQ_ * B_ * 4);
  float* mp     = (float*)alloc((size_t)NSEG_ * CLS_ * 4);   // segmented histogram
  float* perp   = (float*)alloc(256);
  f16* W3h  = (f16*)alloc((size_t)DEPTH_ * 384 * DIM_ * 2);
  f16* W3l  = (f16*)alloc((size_t)DEPTH_ * 384 * DIM_ * 2);
  f16* woh  = (f16*)alloc((size_t)DEPTH_ * DIM_ * INNER_ * 2);
  f16* wol  = (f16*)alloc((size_t)DEPTH_ * DIM_ * INNER_ * 2);
  f16* clsh = (f16*)alloc((size_t)CLS_ * DIM_ * 2);
  f16* clsl = (f16*)alloc((size_t)CLS_ * DIM_ * 2);
  if (off > ws_size) return;

  // arena members (lifetime-disjoint within a layer/step)
  f16*   acth = (f16*)arena;
  f16*   actl = acth + (size_t)B_ * FFI_;
  float* qb   = (float*)arena;
  f16*   obh  = (f16*)(qb + (size_t)B_ * INNER_);
  f16*   obl  = obh + (size_t)B_ * INNER_;
  float* logits = (float*)arena;

  // ---- adaptive tiers ----
  const size_t ff2_bytes = (size_t)DEPTH_ * DIM_ * FFI_ * 2;
  const size_t ff1_bytes = (size_t)DEPTH_ * 2 * FFI_ * DIM_ * 2;
  bool ff2pl = (off + 2 * ff2_bytes <= ws_size);
  f16 *ff2h = nullptr, *ff2l = nullptr;
  if (ff2pl) { ff2h = (f16*)alloc(ff2_bytes); ff2l = (f16*)alloc(ff2_bytes); }
  bool ff1ws = ff2pl && (off + 2 * ff1_bytes <= ws_size);
  f16 *ff1h, *ff1l;
  if (ff1ws) { ff1h = (f16*)alloc(ff1_bytes); ff1l = (f16*)alloc(ff1_bytes); }
  else {
    ff1h = (f16*)outp;                         // d_out scratch (proven r6-r15)
    ff1l = (f16*)((char*)d_out + ff1_bytes);
  }

  unsigned key0[SEQ_], key1[SEQ_];
  for (int i = 0; i < SEQ_; ++i) {
    unsigned a = 0u, b = (unsigned)i;
    tf2x32(0u, 42u, a, b);
    key0[i] = a; key1[i] = b;
  }

  hipMemsetAsync(usedw, 0, (size_t)B_ * CLS_ / 8, stream);
  hipMemsetAsync(mp, 0, (size_t)NSEG_ * CLS_ * 4, stream);
  hipMemsetAsync(perp, 0, 4, stream);

  // ---- build weight planes (z-batched over layers) ----
  tsplit_k<<<dim3(4, 32, DEPTH_), 256, 0, stream>>>(wq, W3h, W3l, 128, 0, 0,   1, DIM_, (size_t)DIM_ * 128, (size_t)384 * DIM_);
  tsplit_k<<<dim3(4, 32, DEPTH_), 256, 0, stream>>>(wk, W3h, W3l, 128, 0, 128, 1, DIM_, (size_t)DIM_ * 128, (size_t)384 * DIM_);
  tsplit_k<<<dim3(4, 32, DEPTH_), 256, 0, stream>>>(wv, W3h, W3l, 128, 0, 256, 1, DIM_, (size_t)DIM_ * 128, (size_t)384 * DIM_);
  tsplit_k<<<dim3(32, 4, DEPTH_), 256, 0, stream>>>(wo, woh, wol, DIM_, 0, 0, 1, INNER_, (size_t)INNER_ * DIM_, (size_t)DIM_ * INNER_);
  tsplit_k<<<dim3(64, 32, DEPTH_), 256, 0, stream>>>(ff_w1, ff1h, ff1l, 2 * FFI_, 0,    0, 2, DIM_, (size_t)DIM_ * 2 * FFI_, (size_t)2 * FFI_ * DIM_);
  tsplit_k<<<dim3(64, 32, DEPTH_), 256, 0, stream>>>(ff_w1, ff1h, ff1l, 2 * FFI_, FFI_, 1, 2, DIM_, (size_t)DIM_ * 2 * FFI_, (size_t)2 * FFI_ * DIM_);
  if (ff2pl)
    tsplit_k<<<dim3(32, 64, DEPTH_), 256, 0, stream>>>(ff_w2, ff2h, ff2l, DIM_, 0, 0, 1, FFI_, (size_t)FFI_ * DIM_, (size_t)DIM_ * FFI_);
  esplit_k<<<(CLS_ * DIM_) / 1024, 256, 0, stream>>>(cls_w, clsh, clsl);
  hipMemcpyAsync(h, x, (size_t)B_ * DIM_ * 4, hipMemcpyDeviceToDevice, stream);

  float* codes_f = outp + (size_t)SEQ_ * B_ * ODIM_ + 1;

  for (int t = 0; t < SEQ_; ++t) {
    for (int l = 0; l < DEPTH_; ++l) {
      float* kc = kcache + (size_t)l * B_ * SEQ_ * INNER_;
      float* vc = vcache + (size_t)l * B_ * SEQ_ * INNER_;
      if (l == 0 && t > 0)
        rmsnorm_split_k<<<B_, 256, 0, stream>>>(nullptr, rms1_g + (size_t)l * DIM_, nh, nl, h, fb_w, idx_all, t - 1);
      else
        rmsnorm_split_k<<<B_, 256, 0, stream>>>(h, rms1_g + (size_t)l * DIM_, nh, nl, nullptr, nullptr, nullptr, 0);
      gemm_pl_k<32, 64, 4><<<dim3(6, 64), 256, 0, stream>>>(nh, nl,
          W3h + (size_t)l * 384 * DIM_, W3l + (size_t)l * 384 * DIM_,
          qb, nullptr, nullptr, nullptr, kc, vc, t, DIM_, 0);
      attn_k<<<B_ / 2, 256, 0, stream>>>(qb, kc, vc, obh, obl, t);
      gemm_pl_k<64, 64, 1><<<dim3(16, 32), 256, 0, stream>>>(obh, obl,
          woh + (size_t)l * DIM_ * INNER_, wol + (size_t)l * DIM_ * INNER_,
          h, nullptr, nullptr, nullptr, nullptr, nullptr, 0, INNER_, DIM_);
      rmsnorm_split_k<<<B_, 256, 0, stream>>>(h, rms2_g + (size_t)l * DIM_, nh, nl, nullptr, nullptr, nullptr, 0);
      gemm_pl_k<64, 128, 3><<<dim3(32, 32), 256, 0, stream>>>(nh, nl,
          ff1h + (size_t)l * 2 * FFI_ * DIM_, ff1l + (size_t)l * 2 * FFI_ * DIM_,
          nullptr, nullptr, acth, actl, nullptr, nullptr, 0, DIM_, 0);
      if (ff2pl) {
        gemm_pl_k<64, 64, 1><<<dim3(16, 32), 256, 0, stream>>>(acth, actl,
            ff2h + (size_t)l * DIM_ * FFI_, ff2l + (size_t)l * DIM_ * FFI_,
            h, nullptr, nullptr, nullptr, nullptr, nullptr, 0, FFI_, DIM_);
      } else {
        tsplit_k<<<dim3(32, 64, 1), 256, 0, stream>>>(ff_w2 + (size_t)l * FFI_ * DIM_,
            nh, nl, DIM_, 0, 0, 1, FFI_, 0, 0);
        gemm_pl_k<64, 64, 1><<<dim3(16, 32), 256, 0, stream>>>(acth, actl,
            nh, nl, h, nullptr, nullptr, nullptr, nullptr, nullptr, 0, FFI_, DIM_);
      }
    }
    rmsnorm_split_k<<<B_, 256, 0, stream>>>(h, final_g, nh, nl, nullptr, nullptr, nullptr, 0);
    gemm_pl_k<64, 64, 2><<<dim3(16, 32), 256, 0, stream>>>(nh, nl,
        clsh, clsl, logits, cls_b, nullptr, nullptr, nullptr, nullptr, 0, DIM_, CLS_);
    sample_k<<<B_, 256, 0, stream>>>(logits, usedw, mp, idx_all, codes_f, key0[t], key1[t], t);
    perp_k<<<1, 256, 0, stream>>>(mp, perp);
  }

  results_k<<<B_, 256, 0, stream>>>(cb_w, idx_all, perp, outp);
}